// Round 15
// baseline (300.089 us; speedup 1.0000x reference)
//
#include <hip/hip_runtime.h>
#include <math.h>
#include <stdio.h>

#define N_NODES 51200
#define N_EDGES 409600
#define B_GRAPH 256
#define NH 13

typedef float v4f __attribute__((ext_vector_type(4)));
typedef unsigned v2u __attribute__((ext_vector_type(2)));
__device__ __forceinline__ void nt_store_u2(uint2* p, uint2 v) {
    v2u w; w.x = v.x; w.y = v.y;
    __builtin_nontemporal_store(w, (v2u*)p);
}

// bf16 pack (RNE) / unpack helpers: payload-only compression for gathers.
__device__ __forceinline__ unsigned pack_bf2(float a, float b) {
    unsigned ua = __float_as_uint(a);
    ua = (ua + 0x7fffu + ((ua >> 16) & 1u)) >> 16;
    unsigned ub = __float_as_uint(b);
    ub = (ub + 0x7fffu + ((ub >> 16) & 1u)) & 0xffff0000u;
    return ua | ub;
}
__device__ __forceinline__ float bf_lo(unsigned u) { return __uint_as_float(u << 16); }
__device__ __forceinline__ float bf_hi(unsigned u) { return __uint_as_float(u & 0xffff0000u); }

// ei dtype probe, inlined: int64 ei has zero high words (uniform scalar loads).
__device__ __forceinline__ bool ei_is_64(const int* __restrict__ ei32) {
    int z = 1;
    #pragma unroll
    for (int k = 1; k < 16; k += 2) z &= (ei32[k] == 0);
    return z != 0;
}

__global__ void count_deg(const int* __restrict__ ei32, const long long* __restrict__ ei64,
                          int* __restrict__ degc) {
    int e = blockIdx.x * 256 + threadIdx.x;
    if (e >= N_EDGES) return;
    int v = ei_is_64(ei32) ? (int)ei64[N_EDGES + e] : ei32[N_EDGES + e];
    atomicAdd(&degc[v], 1);
}

__global__ void scan_block_sums(const int* __restrict__ degc, int* __restrict__ bsums) {
    __shared__ int sdata[256];
    int i = blockIdx.x * 256 + threadIdx.x;
    sdata[threadIdx.x] = degc[i];
    __syncthreads();
    for (int s = 128; s > 0; s >>= 1) {
        if (threadIdx.x < s) sdata[threadIdx.x] += sdata[threadIdx.x + s];
        __syncthreads();
    }
    if (threadIdx.x == 0) bsums[blockIdx.x] = sdata[0];
}

__global__ void scan_finalize(int* __restrict__ degc, int* __restrict__ offs,
                              float* __restrict__ dinv, const int* __restrict__ bsums) {
    __shared__ int bs[256];
    __shared__ int s[256];
    const int t = threadIdx.x;
    bs[t] = (t < 200) ? bsums[t] : 0;
    __syncthreads();
    for (int off = 1; off < 256; off <<= 1) {
        int u = (t >= off) ? bs[t - off] : 0;
        __syncthreads();
        bs[t] += u;
        __syncthreads();
    }
    int i = blockIdx.x * 256 + t;
    int cnt = degc[i];
    s[t] = cnt;
    __syncthreads();
    for (int off = 1; off < 256; off <<= 1) {
        int u = (t >= off) ? s[t - off] : 0;
        __syncthreads();
        s[t] += u;
        __syncthreads();
    }
    int base = (blockIdx.x == 0) ? 0 : bs[blockIdx.x - 1];
    int excl = base + s[t] - cnt;
    offs[i] = excl;
    dinv[i] = rsqrtf((float)(cnt + 1));
    degc[i] = excl;  // fill cursor
    if (i == N_NODES - 1) offs[N_NODES] = N_EDGES;
}

// ---- 64x64 tile body (af path): gather + bias, fp32 out, 4x4/thread ----
template <int K, int WS, bool BF16IN>
__device__ __forceinline__ void gemm_body64(const float* __restrict__ X,
        const float* __restrict__ W, const float* __restrict__ bias,
        float* __restrict__ Y, int row0, const int* __restrict__ rows,
        float* __restrict__ xs, float* __restrict__ ws) {
    constexpr int BK = 32;
    constexpr int XS = BK + 4;
    const int t = threadIdx.x;
    const int ct = t & 15;
    const int rt = t >> 4;
    float acc[4][4] = {{0.f}};
    for (int kc = 0; kc < K; kc += BK) {
        __syncthreads();
        #pragma unroll
        for (int i = 0; i < 2; ++i) {
            int idx = t + i * 256;
            int q = idx & 7, r = idx >> 3;
            int xr = rows[r];
            float4 v;
            if (BF16IN) {
                uint2 pv = ((const uint2*)X)[(size_t)xr * (K / 4) + kc / 4 + q];
                v = make_float4(bf_lo(pv.x), bf_hi(pv.x), bf_lo(pv.y), bf_hi(pv.y));
            } else {
                v = *(const float4*)(X + (size_t)xr * K + kc + q * 4);
            }
            *(float4*)&xs[r * XS + q * 4] = v;
        }
        #pragma unroll
        for (int i = 0; i < 2; ++i) {
            int idx = t + i * 256;
            int q = idx & 15, k = idx >> 4;
            float4 v = *(const float4*)(W + (size_t)(kc + k) * WS + q * 4);
            *(float4*)&ws[k * 64 + q * 4] = v;
        }
        __syncthreads();
        #pragma unroll
        for (int kb = 0; kb < BK; kb += 4) {
            float4 wv[4];
            #pragma unroll
            for (int kk = 0; kk < 4; ++kk)
                wv[kk] = *(const float4*)&ws[(kb + kk) * 64 + ct * 4];
            #pragma unroll
            for (int r = 0; r < 4; ++r) {
                float4 xv = *(const float4*)&xs[(rt * 4 + r) * XS + kb];
                float xk[4] = {xv.x, xv.y, xv.z, xv.w};
                #pragma unroll
                for (int kk = 0; kk < 4; ++kk) {
                    acc[r][0] = fmaf(xk[kk], wv[kk].x, acc[r][0]);
                    acc[r][1] = fmaf(xk[kk], wv[kk].y, acc[r][1]);
                    acc[r][2] = fmaf(xk[kk], wv[kk].z, acc[r][2]);
                    acc[r][3] = fmaf(xk[kk], wv[kk].w, acc[r][3]);
                }
            }
        }
    }
    #pragma unroll
    for (int r = 0; r < 4; ++r) {
        int row = row0 + rt * 4 + r;
        float4 o = make_float4(acc[r][0] + bias[ct * 4 + 0],
                               acc[r][1] + bias[ct * 4 + 1],
                               acc[r][2] + bias[ct * 4 + 2],
                               acc[r][3] + bias[ct * 4 + 3]);
        *(float4*)&Y[(size_t)row * 512 + ct * 4] = o;
    }
}

// ---- main GEMM body: 128-row block, 8 rows x CPT cols per thread.
//      CONFLICT-FREE mappings (round-14 lesson: 1.64M conflicts from
//      8-contiguous-row groups and ct*8 col groups):
//      rows = rt + 16*r  (xs phases 4*rt -> 2-way, free)
//      cols = cq*64 + ct*4 (ws phases 4*ct over contiguous 64 -> 2-way, free) ----
template <int K, int WS, int YS, int NCOLB, int CPT, bool BF16IN, bool BF16OUT>
__device__ __forceinline__ void gemm_main(const float* __restrict__ X,
        const float* __restrict__ W, const float* __restrict__ dinv,
        float* __restrict__ Y, int row0,
        float* __restrict__ xs, float* __restrict__ ws) {
    constexpr int BK = 32;
    constexpr int XS = BK + 4;
    constexpr int CQ = CPT / 4;
    const int t = threadIdx.x;
    const int ct = t & 15;          // 4-col group within each 64-col half
    const int rt = t >> 4;          // row phase (rows rt, rt+16, ..., rt+112)
    float acc[8][CPT];
    #pragma unroll
    for (int r = 0; r < 8; ++r)
        #pragma unroll
        for (int c = 0; c < CPT; ++c) acc[r][c] = 0.f;
    for (int kc = 0; kc < K; kc += BK) {
        __syncthreads();
        // stage x: 128 rows x 32 k, 4 float4/thread (row-major, proven pattern)
        #pragma unroll
        for (int i = 0; i < 4; ++i) {
            int idx = t + i * 256;
            int q = idx & 7, r = idx >> 3;
            float4 v;
            if (BF16IN) {
                uint2 pv = ((const uint2*)X)[(size_t)(row0 + r) * (K / 4) + kc / 4 + q];
                v = make_float4(bf_lo(pv.x), bf_hi(pv.x), bf_lo(pv.y), bf_hi(pv.y));
            } else {
                v = *(const float4*)(X + (size_t)(row0 + r) * K + kc + q * 4);
            }
            *(float4*)&xs[r * XS + q * 4] = v;
        }
        // stage w: 32 k x NCOLB floats (contiguous rows)
        #pragma unroll
        for (int i = 0; i < NCOLB / 32; ++i) {
            int idx = t + i * 256;
            int q = idx & (NCOLB / 4 - 1), k = idx / (NCOLB / 4);
            float4 v = *(const float4*)(W + (size_t)(kc + k) * WS + q * 4);
            *(float4*)&ws[k * NCOLB + q * 4] = v;
        }
        __syncthreads();
        #pragma unroll
        for (int kb = 0; kb < BK; kb += 4) {
            float4 wv[4][CQ];
            #pragma unroll
            for (int kk = 0; kk < 4; ++kk)
                #pragma unroll
                for (int cq = 0; cq < CQ; ++cq)
                    wv[kk][cq] = *(const float4*)&ws[(kb + kk) * NCOLB + cq * 64 + ct * 4];
            #pragma unroll
            for (int r = 0; r < 8; ++r) {
                float4 xv = *(const float4*)&xs[(rt + 16 * r) * XS + kb];
                float xk[4] = {xv.x, xv.y, xv.z, xv.w};
                #pragma unroll
                for (int kk = 0; kk < 4; ++kk)
                    #pragma unroll
                    for (int cq = 0; cq < CQ; ++cq) {
                        acc[r][cq * 4 + 0] = fmaf(xk[kk], wv[kk][cq].x, acc[r][cq * 4 + 0]);
                        acc[r][cq * 4 + 1] = fmaf(xk[kk], wv[kk][cq].y, acc[r][cq * 4 + 1]);
                        acc[r][cq * 4 + 2] = fmaf(xk[kk], wv[kk][cq].z, acc[r][cq * 4 + 2]);
                        acc[r][cq * 4 + 3] = fmaf(xk[kk], wv[kk][cq].w, acc[r][cq * 4 + 3]);
                    }
            }
        }
    }
    #pragma unroll
    for (int r = 0; r < 8; ++r) {
        int row = row0 + rt + 16 * r;
        float sc = dinv[row];
        #pragma unroll
        for (int cq = 0; cq < CQ; ++cq) {
            float4 o = make_float4(acc[r][cq * 4 + 0] * sc, acc[r][cq * 4 + 1] * sc,
                                   acc[r][cq * 4 + 2] * sc, acc[r][cq * 4 + 3] * sc);
            if (BF16OUT) {
                unsigned short* yb = (unsigned short*)Y + (size_t)row * YS;
                uint2 pk;
                pk.x = pack_bf2(o.x, o.y);
                pk.y = pack_bf2(o.z, o.w);
                ((uint2*)yb)[cq * 16 + ct] = pk;
            } else {
                *(float4*)&Y[(size_t)row * YS + cq * 64 + ct * 4] = o;
            }
        }
    }
}

// ---- fused 1: [0,416) af0 | [416,2016) fill_csr | [2016,2816) gemm1
//      (x@W1 -> bf16 xw1b, 128x128 tile, 8x8/thread, conflict-free maps) ----
__global__ __launch_bounds__(256) void fused_gemm1(const float* __restrict__ x,
        const float* __restrict__ W1, float* __restrict__ xw1b,
        const float* __restrict__ dinv,
        const int* __restrict__ ei32, const long long* __restrict__ ei64,
        int* __restrict__ cursor, int* __restrict__ csr,
        const int* __restrict__ host_idx,
        const float* __restrict__ a0W, const float* __restrict__ a0b,
        const float* __restrict__ f0W, const float* __restrict__ f0b,
        float* __restrict__ AF) {
    __shared__ float xs[128 * 36];
    __shared__ float ws[32 * 128];
    __shared__ int rows[64];
    const int bid = blockIdx.x;
    const int t = threadIdx.x;
    if (bid < 416) {
        const int rb = bid >> 3;
        const int cb = bid & 7;
        const int c0 = cb * 64;
        const float* Wp = (c0 < 256) ? (a0W + c0) : (f0W + (c0 - 256));
        const float* bp = (c0 < 256) ? (a0b + c0) : (f0b + (c0 - 256));
        if (t < 64) rows[t] = host_idx[rb * 64 + t];
        __syncthreads();
        gemm_body64<64, 256, false>(x, Wp, bp, AF + c0, rb * 64, rows, xs, ws);
    } else if (bid < 2016) {
        int e = (bid - 416) * 256 + t;
        if (e < N_EDGES) {
            int u, v;
            if (ei_is_64(ei32)) { u = (int)ei64[e]; v = (int)ei64[N_EDGES + e]; }
            else                { u = ei32[e];      v = ei32[N_EDGES + e]; }
            int pos = atomicAdd(&cursor[v], 1);
            csr[pos] = u;
        }
    } else {
        const int gbid = bid - 2016;
        const int rb = gbid >> 1;
        const int cb = gbid & 1;
        // bf16 Y: col-block 128 bf16 elements = 64 floats
        gemm_main<64, 256, 256, 128, 8, false, true>(
            x, W1 + cb * 128, dinv, xw1b + cb * 64, rb * 128, xs, ws);
    }
}

// ---- fused 2: [0,416) af1 (bf16 x1 in) | [416,816) gemm2
//      (x1b@W2 -> fp32 xw2, 128x64 tile, 8x4/thread, conflict-free rows) ----
__global__ __launch_bounds__(256) void fused_gemm2(const float* __restrict__ x1b,
        const float* __restrict__ W2, float* __restrict__ xw2,
        const float* __restrict__ dinv,
        const int* __restrict__ host_idx,
        const float* __restrict__ a1W, const float* __restrict__ a1b,
        const float* __restrict__ f1W, const float* __restrict__ f1b,
        float* __restrict__ AF) {
    __shared__ float xs[128 * 36];
    __shared__ float ws[32 * 64];
    __shared__ int rows[64];
    const int bid = blockIdx.x;
    const int t = threadIdx.x;
    if (bid < 416) {
        const int rb = bid >> 3;
        const int cb = bid & 7;
        const int c0 = cb * 64;
        const float* Wp = (c0 < 256) ? (a1W + c0) : (f1W + (c0 - 256));
        const float* bp = (c0 < 256) ? (a1b + c0) : (f1b + (c0 - 256));
        if (t < 64) rows[t] = host_idx[rb * 64 + t];
        __syncthreads();
        gemm_body64<256, 256, true>(x1b, Wp, bp, AF + c0, rb * 64, rows, xs, ws);
    } else {
        const int gbid = bid - 416;
        gemm_main<256, 64, 64, 64, 4, true, false>(
            x1b, W2, dinv, xw2, gbid * 128, xs, ws);
    }
}

// ---- attn reduce body (H=256): softmax over feats + weighted sum + g update ----
__device__ __forceinline__ void attn_red256(const float* __restrict__ AF,
        const float* __restrict__ gW, const float* __restrict__ gb,
        const float* __restrict__ g_in, float* __restrict__ g_out, int b,
        float (*At)[256], float* red_m, float* red_s, float* cat) {
    const int t = threadIdx.x;
    const int wave = t >> 6, lane = t & 63;
    float accA[NH], accF[NH];
    #pragma unroll
    for (int j = 0; j < NH; ++j) {
        const float* r = AF + (size_t)(b * NH + j) * 512;
        accA[j] = r[t];
        accF[j] = r[256 + t];
        At[j][t] = accA[j];
    }
    __syncthreads();
    for (int j = wave; j < NH; j += 4) {
        float m = -3.402823466e38f;
        #pragma unroll
        for (int q = 0; q < 4; ++q) m = fmaxf(m, At[j][q * 64 + lane]);
        #pragma unroll
        for (int off = 32; off; off >>= 1) m = fmaxf(m, __shfl_xor(m, off));
        if (lane == 0) red_m[j] = m;
    }
    __syncthreads();
    #pragma unroll
    for (int j = 0; j < NH; ++j) At[j][t] = expf(accA[j] - red_m[j]);
    __syncthreads();
    for (int j = wave; j < NH; j += 4) {
        float s = 0.f;
        #pragma unroll
        for (int q = 0; q < 4; ++q) s += At[j][q * 64 + lane];
        #pragma unroll
        for (int off = 32; off; off >>= 1) s += __shfl_xor(s, off);
        if (lane == 0) red_s[j] = s;
    }
    __syncthreads();
    float outc = 0.f;
    #pragma unroll
    for (int j = 0; j < NH; ++j) outc += At[j][t] / red_s[j] * accF[j];
    cat[t] = outc;
    float gv = g_in ? g_in[b * 256 + t] : 0.f;
    cat[256 + t] = gv;
    __syncthreads();
    float acc = gb[t];
    const float* gwp = gW + t;
    #pragma unroll 4
    for (int i4 = 0; i4 < 128; ++i4) {
        float4 cq = ((const float4*)cat)[i4];
        const float* gw4 = gwp + (size_t)i4 * 4 * 256;
        acc = fmaf(cq.x, gw4[0], acc);
        acc = fmaf(cq.y, gw4[256], acc);
        acc = fmaf(cq.z, gw4[512], acc);
        acc = fmaf(cq.w, gw4[768], acc);
    }
    g_out[b * 256 + t] = gv + acc;
}

// ---- fused: [0,256) attn reduce 0 (first), [256,13056) agg_max over bf16
//      rows, OUTPUT bf16 x1b ----
__global__ __launch_bounds__(256) void fused_agg256(const uint2* __restrict__ xwb,
        const float* __restrict__ dinv, const int* __restrict__ offs,
        const int* __restrict__ csr, const float* __restrict__ bias,
        uint2* __restrict__ outb,
        const float* __restrict__ AF, const float* __restrict__ gW,
        const float* __restrict__ gb, const float* __restrict__ g_in,
        float* __restrict__ g_out) {
    __shared__ float At[NH][256];
    __shared__ float red_m[NH];
    __shared__ float red_s[NH];
    __shared__ float cat[512];
    const int bid = blockIdx.x;
    if (bid < 256) {
        attn_red256(AF, gW, gb, g_in, g_out, bid, At, red_m, red_s, cat);
        return;
    }
    int gid = (bid - 256) * 256 + threadIdx.x;
    int v = gid >> 6;
    int lane = gid & 63;
    uint2 sw = xwb[(size_t)v * 64 + lane];  // self (pre-scaled bf16 row)
    float4 acc = make_float4(bf_lo(sw.x), bf_hi(sw.x), bf_lo(sw.y), bf_hi(sw.y));
    int e0 = offs[v];
    int e1 = offs[v + 1];
    int em = e0 + ((e1 - e0) & ~7);
    for (int e = e0; e < em; e += 8) {
        int u[8];
        #pragma unroll
        for (int i = 0; i < 8; ++i) u[i] = csr[e + i];
        uint2 m[8];
        #pragma unroll
        for (int i = 0; i < 8; ++i) m[i] = xwb[(size_t)u[i] * 64 + lane];
        #pragma unroll
        for (int i = 0; i < 8; ++i) {
            acc.x = fmaxf(acc.x, bf_lo(m[i].x));
            acc.y = fmaxf(acc.y, bf_hi(m[i].x));
            acc.z = fmaxf(acc.z, bf_lo(m[i].y));
            acc.w = fmaxf(acc.w, bf_hi(m[i].y));
        }
    }
    if (em < e1) {
        int u[8];
        #pragma unroll
        for (int i = 0; i < 8; ++i) u[i] = csr[(em + i < e1) ? (em + i) : (e1 - 1)];
        uint2 m[8];
        #pragma unroll
        for (int i = 0; i < 8; ++i) m[i] = xwb[(size_t)u[i] * 64 + lane];
        #pragma unroll
        for (int i = 0; i < 8; ++i) {
            if (em + i < e1) {
                acc.x = fmaxf(acc.x, bf_lo(m[i].x));
                acc.y = fmaxf(acc.y, bf_hi(m[i].x));
                acc.z = fmaxf(acc.z, bf_lo(m[i].y));
                acc.w = fmaxf(acc.w, bf_hi(m[i].y));
            }
        }
    }
    float dv = dinv[v];
    float4 b4 = ((const float4*)bias)[lane];
    float4 o;
    o.x = fmaxf(fmaf(acc.x, dv, b4.x), 0.f);
    o.y = fmaxf(fmaf(acc.y, dv, b4.y), 0.f);
    o.z = fmaxf(fmaf(acc.z, dv, b4.z), 0.f);
    o.w = fmaxf(fmaf(acc.w, dv, b4.w), 0.f);
    uint2 pk;
    pk.x = pack_bf2(o.x, o.y);
    pk.y = pack_bf2(o.z, o.w);
    nt_store_u2(outb + (size_t)v * 64 + lane, pk);
}

// ---- per-graph mega-kernel, 1024 threads (verified round 13) ----
__global__ __launch_bounds__(1024) void attn_graph_head(
        const float* __restrict__ AF,
        const float* __restrict__ g1W, const float* __restrict__ g1b,
        const float* __restrict__ g_in,
        const float* __restrict__ xw2,
        const float* __restrict__ dinv, const int* __restrict__ offs,
        const int* __restrict__ csr, const float* __restrict__ b2,
        const int* __restrict__ host_idx,
        const float* __restrict__ a2W, const float* __restrict__ a2b,
        const float* __restrict__ f2W, const float* __restrict__ f2b,
        const float* __restrict__ g2W, const float* __restrict__ g2b,
        const float* __restrict__ o1W, const float* __restrict__ o1b,
        const float* __restrict__ o2W, const float* __restrict__ o2b,
        float* __restrict__ out) {
    __shared__ float At[NH][256];
    __shared__ float Ft[NH][256];
    __shared__ float red_m[NH];
    __shared__ float red_s[NH];
    __shared__ float cat[512];
    __shared__ float catB[320];
    __shared__ float g1s[256];
    __shared__ float x2l[NH][64];
    __shared__ float part4[4][256];
    __shared__ float part16[16][64];
    __shared__ float grow[256];
    const int b = blockIdx.x;
    const int t = threadIdx.x;
    const int wave = t >> 6;
    const int lane = t & 63;
    const int c = t & 255;
    const int quad = t >> 8;

    if (wave < NH) {
        int hv = host_idx[b * NH + wave];
        float acc = xw2[(size_t)hv * 64 + lane];
        int e0 = offs[hv], e1 = offs[hv + 1];
        for (int e = e0; e < e1; e += 8) {
            int u[8];
            #pragma unroll
            for (int i = 0; i < 8; ++i) u[i] = csr[(e + i < e1) ? (e + i) : (e1 - 1)];
            float m[8];
            #pragma unroll
            for (int i = 0; i < 8; ++i) m[i] = xw2[(size_t)u[i] * 64 + lane];
            #pragma unroll
            for (int i = 0; i < 8; ++i)
                if (e + i < e1) acc = fmaxf(acc, m[i]);
        }
        x2l[wave][lane] = fmaxf(fmaf(acc, dinv[hv], b2[lane]), 0.f);
    }
    for (int idx = t; idx < NH * 128; idx += 1024) {
        int j = idx >> 7, q = idx & 127;
        float4 v = ((const float4*)(AF + (size_t)(b * NH + j) * 512))[q];
        if (q < 64) *(float4*)&At[j][q * 4] = v;
        else        *(float4*)&Ft[j][(q - 64) * 4] = v;
    }
    __syncthreads();
    if (wave < NH) {
        float m = -3.402823466e38f;
        #pragma unroll
        for (int q = 0; q < 4; ++q) m = fmaxf(m, At[wave][q * 64 + lane]);
        #pragma unroll
        for (int off = 32; off; off >>= 1) m = fmaxf(m, __shfl_xor(m, off));
        if (lane == 0) red_m[wave] = m;
    }
    __syncthreads();
    for (int idx = t; idx < NH * 256; idx += 1024) {
        int j = idx >> 8, cc = idx & 255;
        At[j][cc] = expf(At[j][cc] - red_m[j]);
    }
    __syncthreads();
    if (wave < NH) {
        float s = 0.f;
        #pragma unroll
        for (int q = 0; q < 4; ++q) s += At[wave][q * 64 + lane];
        #pragma unroll
        for (int off = 32; off; off >>= 1) s += __shfl_xor(s, off);
        if (lane == 0) red_s[wave] = s;
    }
    __syncthreads();
    if (quad == 0) {
        float outc = 0.f;
        #pragma unroll
        for (int j = 0; j < NH; ++j) outc += At[j][c] / red_s[j] * Ft[j][c];
        cat[c] = outc;
        cat[256 + c] = g_in[b * 256 + c];
    }
    __syncthreads();
    // g1W update: 512 floats = 128 float4, 32 per quad (full coverage)
    {
        float acc = 0.f;
        const float* gwp = g1W + c;
        #pragma unroll 4
        for (int i4 = quad * 32; i4 < quad * 32 + 32; ++i4) {
            float4 cq = ((const float4*)cat)[i4];
            const float* gw4 = gwp + (size_t)i4 * 1024;
            acc = fmaf(cq.x, gw4[0], acc);
            acc = fmaf(cq.y, gw4[256], acc);
            acc = fmaf(cq.z, gw4[512], acc);
            acc = fmaf(cq.w, gw4[768], acc);
        }
        part4[quad][c] = acc;
    }
    __syncthreads();
    if (quad == 0)
        g1s[c] = cat[256 + c] + g1b[c] +
                 part4[0][c] + part4[1][c] + part4[2][c] + part4[3][c];
    __syncthreads();
    if (wave < NH) {
        float aA = a2b[lane], aF = f2b[lane];
        #pragma unroll 8
        for (int k = 0; k < 64; ++k) {
            float xv = x2l[wave][k];
            aA = fmaf(xv, a2W[k * 64 + lane], aA);
            aF = fmaf(xv, f2W[k * 64 + lane], aF);
        }
        float m = aA;
        #pragma unroll
        for (int off = 32; off; off >>= 1) m = fmaxf(m, __shfl_xor(m, off));
        float pexp = expf(aA - m);
        float s = pexp;
        #pragma unroll
        for (int off = 32; off; off >>= 1) s += __shfl_xor(s, off);
        At[wave][lane] = pexp / s * aF;
    }
    __syncthreads();
    if (t < 64) {
        float o = 0.f;
        #pragma unroll
        for (int j = 0; j < NH; ++j) o += At[j][t];
        catB[t] = o;
    }
    if (quad == 0) catB[64 + c] = g1s[c];
    __syncthreads();
    // g2W update: 320 floats = 80 float4, 20 per quad
    {
        float acc = 0.f;
        const float* gwp = g2W + c;
        #pragma unroll 4
        for (int i4 = quad * 20; i4 < quad * 20 + 20; ++i4) {
            float4 cq = ((const float4*)catB)[i4];
            const float* gw4 = gwp + (size_t)i4 * 1024;
            acc = fmaf(cq.x, gw4[0], acc);
            acc = fmaf(cq.y, gw4[256], acc);
            acc = fmaf(cq.z, gw4[512], acc);
            acc = fmaf(cq.w, gw4[768], acc);
        }
        part4[quad][c] = acc;
    }
    __syncthreads();
    if (quad == 0)
        grow[c] = g1s[c] + g2b[c] +
                  part4[0][c] + part4[1][c] + part4[2][c] + part4[3][c];
    __syncthreads();
    {
        float hp = 0.f;
        #pragma unroll
        for (int k = wave * 16; k < wave * 16 + 16; ++k)
            hp = fmaf(grow[k], o1W[(size_t)k * 64 + lane], hp);
        part16[wave][lane] = hp;
    }
    __syncthreads();
    if (wave == 0) {
        float h = o1b[lane];
        #pragma unroll
        for (int w = 0; w < 16; ++w) h += part16[w][lane];
        h = fmaxf(h, 0.f);
        float sres = h * o2W[lane];
        #pragma unroll
        for (int off = 32; off; off >>= 1) sres += __shfl_xor(sres, off);
        if (lane == 0) out[b] = sres + o2b[0];
    }
}

extern "C" void kernel_launch(void* const* d_in, const int* in_sizes, int n_in,
                              void* d_out, int out_size, void* d_ws, size_t ws_size,
                              hipStream_t stream) {
    (void)in_sizes; (void)n_in; (void)out_size;
    const float* x    = (const float*)d_in[0];
    const int* ei32   = (const int*)d_in[1];
    const long long* ei64 = (const long long*)d_in[1];
    const int* hidx   = (const int*)d_in[2];
    const float* W1 = (const float*)d_in[3],  *b1 = (const float*)d_in[4];
    const float* W2 = (const float*)d_in[5],  *b2 = (const float*)d_in[6];
    const float* a0W = (const float*)d_in[7],  *a0b = (const float*)d_in[8];
    const float* f0W = (const float*)d_in[9],  *f0b = (const float*)d_in[10];
    const float* g0W = (const float*)d_in[11], *g0b = (const float*)d_in[12];
    const float* a1W = (const float*)d_in[13], *a1b = (const float*)d_in[14];
    const float* f1W = (const float*)d_in[15], *f1b = (const float*)d_in[16];
    const float* g1W = (const float*)d_in[17], *g1b = (const float*)d_in[18];
    const float* a2W = (const float*)d_in[19], *a2b = (const float*)d_in[20];
    const float* f2W = (const float*)d_in[21], *f2b = (const float*)d_in[22];
    const float* g2W = (const float*)d_in[23], *g2b = (const float*)d_in[24];
    const float* o1W = (const float*)d_in[25], *o1b = (const float*)d_in[26];
    const float* o2W = (const float*)d_in[27], *o2b = (const float*)d_in[28];
    float* outp = (float*)d_out;

    char* p = (char*)d_ws;
    auto alloc = [&](size_t bytes) {
        char* r = p;
        p += (bytes + 255) & ~(size_t)255;
        return r;
    };
    float* dinv = (float*)alloc((size_t)N_NODES * 4);
    int* degc   = (int*)alloc((size_t)N_NODES * 4);
    int* offs   = (int*)alloc((size_t)(N_NODES + 1) * 4);
    int* csr    = (int*)alloc((size_t)N_EDGES * 4);
    int* bsums  = (int*)alloc(256 * 4);
    float* g    = (float*)alloc((size_t)B_GRAPH * 256 * 4);
    float* AF   = (float*)alloc((size_t)B_GRAPH * NH * 512 * 4);
    unsigned short* xw1b = (unsigned short*)alloc((size_t)N_NODES * 256 * 2);  // bf16
    unsigned short* x1b  = (unsigned short*)alloc((size_t)N_NODES * 256 * 2);  // bf16
    float* xw2  = (float*)alloc((size_t)N_NODES * 64 * 4);

    size_t need = (size_t)(p - (char*)d_ws);
    if (need > ws_size) {
        fprintf(stderr, "kernel_launch: ws too small (%zu needed, %zu have)\n", need, ws_size);
        return;
    }

    (void)hipMemsetAsync(degc, 0, (size_t)N_NODES * 4, stream);
    count_deg<<<1600, 256, 0, stream>>>(ei32, ei64, degc);
    scan_block_sums<<<200, 256, 0, stream>>>(degc, bsums);
    scan_finalize<<<200, 256, 0, stream>>>(degc, offs, dinv, bsums);

    // af0 | fill_csr | gemm1 (128x128, bf16 out)
    fused_gemm1<<<2816, 256, 0, stream>>>(
        x, W1, (float*)xw1b, dinv, ei32, ei64, degc, csr,
        hidx, a0W, a0b, f0W, f0b, AF);
    // attn reduce 0 | agg (bf16 gather, bf16 out)
    fused_agg256<<<256 + 12800, 256, 0, stream>>>((const uint2*)xw1b, dinv, offs, csr,
                                                  b1, (uint2*)x1b, AF, g0W, g0b,
                                                  nullptr, g);
    // af1 (bf16 in) | gemm2 (128x64, bf16 in, fp32 out)
    fused_gemm2<<<816, 256, 0, stream>>>(
        (const float*)x1b, W2, xw2, dinv, hidx, a1W, a1b, f1W, f1b, AF);
    // per-graph (1024 thr): reduce1 + host-only agg + attn2 + g2 update + head
    attn_graph_head<<<256, 1024, 0, stream>>>(
        AF, g1W, g1b, g, xw2, dinv, offs, csr, b2, hidx,
        a2W, a2b, f2W, f2b, g2W, g2b, o1W, o1b, o2W, o2b, outp);
}

// Round 16
// 282.419 us; speedup vs baseline: 1.0626x; 1.0626x over previous
//
#include <hip/hip_runtime.h>
#include <math.h>
#include <stdio.h>

#define N_NODES 51200
#define N_EDGES 409600
#define B_GRAPH 256
#define NH 13

typedef float v4f __attribute__((ext_vector_type(4)));
typedef unsigned v2u __attribute__((ext_vector_type(2)));
__device__ __forceinline__ void nt_store_u2(uint2* p, uint2 v) {
    v2u w; w.x = v.x; w.y = v.y;
    __builtin_nontemporal_store(w, (v2u*)p);
}

// bf16 pack (RNE) / unpack helpers: payload-only compression for gathers.
__device__ __forceinline__ unsigned pack_bf2(float a, float b) {
    unsigned ua = __float_as_uint(a);
    ua = (ua + 0x7fffu + ((ua >> 16) & 1u)) >> 16;
    unsigned ub = __float_as_uint(b);
    ub = (ub + 0x7fffu + ((ub >> 16) & 1u)) & 0xffff0000u;
    return ua | ub;
}
__device__ __forceinline__ float bf_lo(unsigned u) { return __uint_as_float(u << 16); }
__device__ __forceinline__ float bf_hi(unsigned u) { return __uint_as_float(u & 0xffff0000u); }

// ei dtype probe, inlined: int64 ei has zero high words (uniform scalar loads).
__device__ __forceinline__ bool ei_is_64(const int* __restrict__ ei32) {
    int z = 1;
    #pragma unroll
    for (int k = 1; k < 16; k += 2) z &= (ei32[k] == 0);
    return z != 0;
}

__global__ void count_deg(const int* __restrict__ ei32, const long long* __restrict__ ei64,
                          int* __restrict__ degc) {
    int e = blockIdx.x * 256 + threadIdx.x;
    if (e >= N_EDGES) return;
    int v = ei_is_64(ei32) ? (int)ei64[N_EDGES + e] : ei32[N_EDGES + e];
    atomicAdd(&degc[v], 1);
}

__global__ void scan_block_sums(const int* __restrict__ degc, int* __restrict__ bsums) {
    __shared__ int sdata[256];
    int i = blockIdx.x * 256 + threadIdx.x;
    sdata[threadIdx.x] = degc[i];
    __syncthreads();
    for (int s = 128; s > 0; s >>= 1) {
        if (threadIdx.x < s) sdata[threadIdx.x] += sdata[threadIdx.x + s];
        __syncthreads();
    }
    if (threadIdx.x == 0) bsums[blockIdx.x] = sdata[0];
}

__global__ void scan_finalize(int* __restrict__ degc, int* __restrict__ offs,
                              float* __restrict__ dinv, const int* __restrict__ bsums) {
    __shared__ int bs[256];
    __shared__ int s[256];
    const int t = threadIdx.x;
    bs[t] = (t < 200) ? bsums[t] : 0;
    __syncthreads();
    for (int off = 1; off < 256; off <<= 1) {
        int u = (t >= off) ? bs[t - off] : 0;
        __syncthreads();
        bs[t] += u;
        __syncthreads();
    }
    int i = blockIdx.x * 256 + t;
    int cnt = degc[i];
    s[t] = cnt;
    __syncthreads();
    for (int off = 1; off < 256; off <<= 1) {
        int u = (t >= off) ? s[t - off] : 0;
        __syncthreads();
        s[t] += u;
        __syncthreads();
    }
    int base = (blockIdx.x == 0) ? 0 : bs[blockIdx.x - 1];
    int excl = base + s[t] - cnt;
    offs[i] = excl;
    dinv[i] = rsqrtf((float)(cnt + 1));
    degc[i] = excl;  // fill cursor
    if (i == N_NODES - 1) offs[N_NODES] = N_EDGES;
}

// ---- 64x64 tile body (af path): gather + bias, fp32 out, 4x4/thread ----
template <int K, int WS, bool BF16IN>
__device__ __forceinline__ void gemm_body64(const float* __restrict__ X,
        const float* __restrict__ W, const float* __restrict__ bias,
        float* __restrict__ Y, int row0, const int* __restrict__ rows,
        float* __restrict__ xs, float* __restrict__ ws) {
    constexpr int BK = 32;
    constexpr int XS = BK + 4;
    const int t = threadIdx.x;
    const int ct = t & 15;
    const int rt = t >> 4;
    float acc[4][4] = {{0.f}};
    for (int kc = 0; kc < K; kc += BK) {
        __syncthreads();
        #pragma unroll
        for (int i = 0; i < 2; ++i) {
            int idx = t + i * 256;
            int q = idx & 7, r = idx >> 3;
            int xr = rows[r];
            float4 v;
            if (BF16IN) {
                uint2 pv = ((const uint2*)X)[(size_t)xr * (K / 4) + kc / 4 + q];
                v = make_float4(bf_lo(pv.x), bf_hi(pv.x), bf_lo(pv.y), bf_hi(pv.y));
            } else {
                v = *(const float4*)(X + (size_t)xr * K + kc + q * 4);
            }
            *(float4*)&xs[r * XS + q * 4] = v;
        }
        #pragma unroll
        for (int i = 0; i < 2; ++i) {
            int idx = t + i * 256;
            int q = idx & 15, k = idx >> 4;
            float4 v = *(const float4*)(W + (size_t)(kc + k) * WS + q * 4);
            *(float4*)&ws[k * 64 + q * 4] = v;
        }
        __syncthreads();
        #pragma unroll
        for (int kb = 0; kb < BK; kb += 4) {
            float4 wv[4];
            #pragma unroll
            for (int kk = 0; kk < 4; ++kk)
                wv[kk] = *(const float4*)&ws[(kb + kk) * 64 + ct * 4];
            #pragma unroll
            for (int r = 0; r < 4; ++r) {
                float4 xv = *(const float4*)&xs[(rt * 4 + r) * XS + kb];
                float xk[4] = {xv.x, xv.y, xv.z, xv.w};
                #pragma unroll
                for (int kk = 0; kk < 4; ++kk) {
                    acc[r][0] = fmaf(xk[kk], wv[kk].x, acc[r][0]);
                    acc[r][1] = fmaf(xk[kk], wv[kk].y, acc[r][1]);
                    acc[r][2] = fmaf(xk[kk], wv[kk].z, acc[r][2]);
                    acc[r][3] = fmaf(xk[kk], wv[kk].w, acc[r][3]);
                }
            }
        }
    }
    #pragma unroll
    for (int r = 0; r < 4; ++r) {
        int row = row0 + rt * 4 + r;
        float4 o = make_float4(acc[r][0] + bias[ct * 4 + 0],
                               acc[r][1] + bias[ct * 4 + 1],
                               acc[r][2] + bias[ct * 4 + 2],
                               acc[r][3] + bias[ct * 4 + 3]);
        *(float4*)&Y[(size_t)row * 512 + ct * 4] = o;
    }
}

// ---- 64x64 main-GEMM body (round-13 proven, 4x4/thread, conflict-free):
//      dinv prescale, bf16 out. 18 KB LDS -> high block count & occupancy. ----
template <int K, int WS, int YS, bool BF16OUT>
__device__ __forceinline__ void gemm_main64(const float* __restrict__ X,
        const float* __restrict__ W, const float* __restrict__ dinv,
        float* __restrict__ Y, int row0,
        float* __restrict__ xs, float* __restrict__ ws) {
    constexpr int BK = 32;
    constexpr int XS = BK + 4;
    const int t = threadIdx.x;
    const int ct = t & 15;
    const int rt = t >> 4;
    float acc[4][4] = {{0.f}};
    for (int kc = 0; kc < K; kc += BK) {
        __syncthreads();
        #pragma unroll
        for (int i = 0; i < 2; ++i) {
            int idx = t + i * 256;
            int q = idx & 7, r = idx >> 3;
            float4 v = *(const float4*)(X + (size_t)(row0 + r) * K + kc + q * 4);
            *(float4*)&xs[r * XS + q * 4] = v;
        }
        #pragma unroll
        for (int i = 0; i < 2; ++i) {
            int idx = t + i * 256;
            int q = idx & 15, k = idx >> 4;
            float4 v = *(const float4*)(W + (size_t)(kc + k) * WS + q * 4);
            *(float4*)&ws[k * 64 + q * 4] = v;
        }
        __syncthreads();
        #pragma unroll
        for (int kb = 0; kb < BK; kb += 4) {
            float4 wv[4];
            #pragma unroll
            for (int kk = 0; kk < 4; ++kk)
                wv[kk] = *(const float4*)&ws[(kb + kk) * 64 + ct * 4];
            #pragma unroll
            for (int r = 0; r < 4; ++r) {
                float4 xv = *(const float4*)&xs[(rt * 4 + r) * XS + kb];
                float xk[4] = {xv.x, xv.y, xv.z, xv.w};
                #pragma unroll
                for (int kk = 0; kk < 4; ++kk) {
                    acc[r][0] = fmaf(xk[kk], wv[kk].x, acc[r][0]);
                    acc[r][1] = fmaf(xk[kk], wv[kk].y, acc[r][1]);
                    acc[r][2] = fmaf(xk[kk], wv[kk].z, acc[r][2]);
                    acc[r][3] = fmaf(xk[kk], wv[kk].w, acc[r][3]);
                }
            }
        }
    }
    #pragma unroll
    for (int r = 0; r < 4; ++r) {
        int row = row0 + rt * 4 + r;
        float sc = dinv[row];
        float4 o = make_float4(acc[r][0] * sc, acc[r][1] * sc,
                               acc[r][2] * sc, acc[r][3] * sc);
        if (BF16OUT) {
            unsigned short* yb = (unsigned short*)Y + (size_t)row * YS;
            uint2 pk;
            pk.x = pack_bf2(o.x, o.y);
            pk.y = pack_bf2(o.z, o.w);
            ((uint2*)yb)[ct] = pk;
        } else {
            *(float4*)&Y[(size_t)row * YS + ct * 4] = o;
        }
    }
}

// ---- 128-row main GEMM (8 rows x CPT cols/thread, conflict-free maps,
//      round-15 verified for gemm2): rows rt+16r, cols cq*64+ct*4 ----
template <int K, int WS, int YS, int NCOLB, int CPT, bool BF16IN, bool BF16OUT>
__device__ __forceinline__ void gemm_main(const float* __restrict__ X,
        const float* __restrict__ W, const float* __restrict__ dinv,
        float* __restrict__ Y, int row0,
        float* __restrict__ xs, float* __restrict__ ws) {
    constexpr int BK = 32;
    constexpr int XS = BK + 4;
    constexpr int CQ = CPT / 4;
    const int t = threadIdx.x;
    const int ct = t & 15;
    const int rt = t >> 4;
    float acc[8][CPT];
    #pragma unroll
    for (int r = 0; r < 8; ++r)
        #pragma unroll
        for (int c = 0; c < CPT; ++c) acc[r][c] = 0.f;
    for (int kc = 0; kc < K; kc += BK) {
        __syncthreads();
        #pragma unroll
        for (int i = 0; i < 4; ++i) {
            int idx = t + i * 256;
            int q = idx & 7, r = idx >> 3;
            float4 v;
            if (BF16IN) {
                uint2 pv = ((const uint2*)X)[(size_t)(row0 + r) * (K / 4) + kc / 4 + q];
                v = make_float4(bf_lo(pv.x), bf_hi(pv.x), bf_lo(pv.y), bf_hi(pv.y));
            } else {
                v = *(const float4*)(X + (size_t)(row0 + r) * K + kc + q * 4);
            }
            *(float4*)&xs[r * XS + q * 4] = v;
        }
        #pragma unroll
        for (int i = 0; i < NCOLB / 32; ++i) {
            int idx = t + i * 256;
            int q = idx & (NCOLB / 4 - 1), k = idx / (NCOLB / 4);
            float4 v = *(const float4*)(W + (size_t)(kc + k) * WS + q * 4);
            *(float4*)&ws[k * NCOLB + q * 4] = v;
        }
        __syncthreads();
        #pragma unroll
        for (int kb = 0; kb < BK; kb += 4) {
            float4 wv[4][CQ];
            #pragma unroll
            for (int kk = 0; kk < 4; ++kk)
                #pragma unroll
                for (int cq = 0; cq < CQ; ++cq)
                    wv[kk][cq] = *(const float4*)&ws[(kb + kk) * NCOLB + cq * 64 + ct * 4];
            #pragma unroll
            for (int r = 0; r < 8; ++r) {
                float4 xv = *(const float4*)&xs[(rt + 16 * r) * XS + kb];
                float xk[4] = {xv.x, xv.y, xv.z, xv.w};
                #pragma unroll
                for (int kk = 0; kk < 4; ++kk)
                    #pragma unroll
                    for (int cq = 0; cq < CQ; ++cq) {
                        acc[r][cq * 4 + 0] = fmaf(xk[kk], wv[kk][cq].x, acc[r][cq * 4 + 0]);
                        acc[r][cq * 4 + 1] = fmaf(xk[kk], wv[kk][cq].y, acc[r][cq * 4 + 1]);
                        acc[r][cq * 4 + 2] = fmaf(xk[kk], wv[kk][cq].z, acc[r][cq * 4 + 2]);
                        acc[r][cq * 4 + 3] = fmaf(xk[kk], wv[kk][cq].w, acc[r][cq * 4 + 3]);
                    }
            }
        }
    }
    #pragma unroll
    for (int r = 0; r < 8; ++r) {
        int row = row0 + rt + 16 * r;
        float sc = dinv[row];
        #pragma unroll
        for (int cq = 0; cq < CQ; ++cq) {
            float4 o = make_float4(acc[r][cq * 4 + 0] * sc, acc[r][cq * 4 + 1] * sc,
                                   acc[r][cq * 4 + 2] * sc, acc[r][cq * 4 + 3] * sc);
            if (BF16OUT) {
                unsigned short* yb = (unsigned short*)Y + (size_t)row * YS;
                uint2 pk;
                pk.x = pack_bf2(o.x, o.y);
                pk.y = pack_bf2(o.z, o.w);
                ((uint2*)yb)[cq * 16 + ct] = pk;
            } else {
                *(float4*)&Y[(size_t)row * YS + cq * 64 + ct * 4] = o;
            }
        }
    }
}

// ---- fused 1: [0,3200) gemm1 FIRST (heavy blocks start at t=0; round-15
//      lesson: late-start tail), [3200,3616) af0, [3616,5216) fill_csr ----
__global__ __launch_bounds__(256) void fused_gemm1(const float* __restrict__ x,
        const float* __restrict__ W1, float* __restrict__ xw1b,
        const float* __restrict__ dinv,
        const int* __restrict__ ei32, const long long* __restrict__ ei64,
        int* __restrict__ cursor, int* __restrict__ csr,
        const int* __restrict__ host_idx,
        const float* __restrict__ a0W, const float* __restrict__ a0b,
        const float* __restrict__ f0W, const float* __restrict__ f0b,
        float* __restrict__ AF) {
    __shared__ float xs[64 * 36];
    __shared__ float ws[32 * 64];
    __shared__ int rows[64];
    const int bid = blockIdx.x;
    const int t = threadIdx.x;
    if (bid < 3200) {
        const int rb = bid >> 2;
        const int cb = bid & 3;
        // bf16 Y: col-block 64 bf16 elements = 32 floats
        gemm_main64<64, 256, 256, true>(
            x, W1 + cb * 64, dinv, xw1b + cb * 32, rb * 64, xs, ws);
    } else if (bid < 3616) {
        const int abid = bid - 3200;
        const int rb = abid >> 3;
        const int cb = abid & 7;
        const int c0 = cb * 64;
        const float* Wp = (c0 < 256) ? (a0W + c0) : (f0W + (c0 - 256));
        const float* bp = (c0 < 256) ? (a0b + c0) : (f0b + (c0 - 256));
        if (t < 64) rows[t] = host_idx[rb * 64 + t];
        __syncthreads();
        gemm_body64<64, 256, false>(x, Wp, bp, AF + c0, rb * 64, rows, xs, ws);
    } else {
        int e = (bid - 3616) * 256 + t;
        if (e < N_EDGES) {
            int u, v;
            if (ei_is_64(ei32)) { u = (int)ei64[e]; v = (int)ei64[N_EDGES + e]; }
            else                { u = ei32[e];      v = ei32[N_EDGES + e]; }
            int pos = atomicAdd(&cursor[v], 1);
            csr[pos] = u;
        }
    }
}

// ---- fused 2: [0,400) gemm2 FIRST (128x64, 8x4, bf16 in, fp32 out),
//      [400,816) af1 (bf16 x1 in) ----
__global__ __launch_bounds__(256) void fused_gemm2(const float* __restrict__ x1b,
        const float* __restrict__ W2, float* __restrict__ xw2,
        const float* __restrict__ dinv,
        const int* __restrict__ host_idx,
        const float* __restrict__ a1W, const float* __restrict__ a1b,
        const float* __restrict__ f1W, const float* __restrict__ f1b,
        float* __restrict__ AF) {
    __shared__ float xs[128 * 36];
    __shared__ float ws[32 * 64];
    __shared__ int rows[64];
    const int bid = blockIdx.x;
    const int t = threadIdx.x;
    if (bid < 400) {
        gemm_main<256, 64, 64, 64, 4, true, false>(
            x1b, W2, dinv, xw2, bid * 128, xs, ws);
    } else {
        const int abid = bid - 400;
        const int rb = abid >> 3;
        const int cb = abid & 7;
        const int c0 = cb * 64;
        const float* Wp = (c0 < 256) ? (a1W + c0) : (f1W + (c0 - 256));
        const float* bp = (c0 < 256) ? (a1b + c0) : (f1b + (c0 - 256));
        if (t < 64) rows[t] = host_idx[rb * 64 + t];
        __syncthreads();
        gemm_body64<256, 256, true>(x1b, Wp, bp, AF + c0, rb * 64, rows, xs, ws);
    }
}

// ---- attn reduce body (H=256): softmax over feats + weighted sum + g update ----
__device__ __forceinline__ void attn_red256(const float* __restrict__ AF,
        const float* __restrict__ gW, const float* __restrict__ gb,
        const float* __restrict__ g_in, float* __restrict__ g_out, int b,
        float (*At)[256], float* red_m, float* red_s, float* cat) {
    const int t = threadIdx.x;
    const int wave = t >> 6, lane = t & 63;
    float accA[NH], accF[NH];
    #pragma unroll
    for (int j = 0; j < NH; ++j) {
        const float* r = AF + (size_t)(b * NH + j) * 512;
        accA[j] = r[t];
        accF[j] = r[256 + t];
        At[j][t] = accA[j];
    }
    __syncthreads();
    for (int j = wave; j < NH; j += 4) {
        float m = -3.402823466e38f;
        #pragma unroll
        for (int q = 0; q < 4; ++q) m = fmaxf(m, At[j][q * 64 + lane]);
        #pragma unroll
        for (int off = 32; off; off >>= 1) m = fmaxf(m, __shfl_xor(m, off));
        if (lane == 0) red_m[j] = m;
    }
    __syncthreads();
    #pragma unroll
    for (int j = 0; j < NH; ++j) At[j][t] = expf(accA[j] - red_m[j]);
    __syncthreads();
    for (int j = wave; j < NH; j += 4) {
        float s = 0.f;
        #pragma unroll
        for (int q = 0; q < 4; ++q) s += At[j][q * 64 + lane];
        #pragma unroll
        for (int off = 32; off; off >>= 1) s += __shfl_xor(s, off);
        if (lane == 0) red_s[j] = s;
    }
    __syncthreads();
    float outc = 0.f;
    #pragma unroll
    for (int j = 0; j < NH; ++j) outc += At[j][t] / red_s[j] * accF[j];
    cat[t] = outc;
    float gv = g_in ? g_in[b * 256 + t] : 0.f;
    cat[256 + t] = gv;
    __syncthreads();
    float acc = gb[t];
    const float* gwp = gW + t;
    #pragma unroll 4
    for (int i4 = 0; i4 < 128; ++i4) {
        float4 cq = ((const float4*)cat)[i4];
        const float* gw4 = gwp + (size_t)i4 * 4 * 256;
        acc = fmaf(cq.x, gw4[0], acc);
        acc = fmaf(cq.y, gw4[256], acc);
        acc = fmaf(cq.z, gw4[512], acc);
        acc = fmaf(cq.w, gw4[768], acc);
    }
    g_out[b * 256 + t] = gv + acc;
}

// ---- fused: [0,256) attn reduce 0 (first), [256,13056) agg_max over bf16
//      rows, OUTPUT bf16 x1b ----
__global__ __launch_bounds__(256) void fused_agg256(const uint2* __restrict__ xwb,
        const float* __restrict__ dinv, const int* __restrict__ offs,
        const int* __restrict__ csr, const float* __restrict__ bias,
        uint2* __restrict__ outb,
        const float* __restrict__ AF, const float* __restrict__ gW,
        const float* __restrict__ gb, const float* __restrict__ g_in,
        float* __restrict__ g_out) {
    __shared__ float At[NH][256];
    __shared__ float red_m[NH];
    __shared__ float red_s[NH];
    __shared__ float cat[512];
    const int bid = blockIdx.x;
    if (bid < 256) {
        attn_red256(AF, gW, gb, g_in, g_out, bid, At, red_m, red_s, cat);
        return;
    }
    int gid = (bid - 256) * 256 + threadIdx.x;
    int v = gid >> 6;
    int lane = gid & 63;
    uint2 sw = xwb[(size_t)v * 64 + lane];  // self (pre-scaled bf16 row)
    float4 acc = make_float4(bf_lo(sw.x), bf_hi(sw.x), bf_lo(sw.y), bf_hi(sw.y));
    int e0 = offs[v];
    int e1 = offs[v + 1];
    int em = e0 + ((e1 - e0) & ~7);
    for (int e = e0; e < em; e += 8) {
        int u[8];
        #pragma unroll
        for (int i = 0; i < 8; ++i) u[i] = csr[e + i];
        uint2 m[8];
        #pragma unroll
        for (int i = 0; i < 8; ++i) m[i] = xwb[(size_t)u[i] * 64 + lane];
        #pragma unroll
        for (int i = 0; i < 8; ++i) {
            acc.x = fmaxf(acc.x, bf_lo(m[i].x));
            acc.y = fmaxf(acc.y, bf_hi(m[i].x));
            acc.z = fmaxf(acc.z, bf_lo(m[i].y));
            acc.w = fmaxf(acc.w, bf_hi(m[i].y));
        }
    }
    if (em < e1) {
        int u[8];
        #pragma unroll
        for (int i = 0; i < 8; ++i) u[i] = csr[(em + i < e1) ? (em + i) : (e1 - 1)];
        uint2 m[8];
        #pragma unroll
        for (int i = 0; i < 8; ++i) m[i] = xwb[(size_t)u[i] * 64 + lane];
        #pragma unroll
        for (int i = 0; i < 8; ++i) {
            if (em + i < e1) {
                acc.x = fmaxf(acc.x, bf_lo(m[i].x));
                acc.y = fmaxf(acc.y, bf_hi(m[i].x));
                acc.z = fmaxf(acc.z, bf_lo(m[i].y));
                acc.w = fmaxf(acc.w, bf_hi(m[i].y));
            }
        }
    }
    float dv = dinv[v];
    float4 b4 = ((const float4*)bias)[lane];
    float4 o;
    o.x = fmaxf(fmaf(acc.x, dv, b4.x), 0.f);
    o.y = fmaxf(fmaf(acc.y, dv, b4.y), 0.f);
    o.z = fmaxf(fmaf(acc.z, dv, b4.z), 0.f);
    o.w = fmaxf(fmaf(acc.w, dv, b4.w), 0.f);
    uint2 pk;
    pk.x = pack_bf2(o.x, o.y);
    pk.y = pack_bf2(o.z, o.w);
    nt_store_u2(outb + (size_t)v * 64 + lane, pk);
}

// ---- per-graph mega-kernel, 1024 threads (verified round 13) ----
__global__ __launch_bounds__(1024) void attn_graph_head(
        const float* __restrict__ AF,
        const float* __restrict__ g1W, const float* __restrict__ g1b,
        const float* __restrict__ g_in,
        const float* __restrict__ xw2,
        const float* __restrict__ dinv, const int* __restrict__ offs,
        const int* __restrict__ csr, const float* __restrict__ b2,
        const int* __restrict__ host_idx,
        const float* __restrict__ a2W, const float* __restrict__ a2b,
        const float* __restrict__ f2W, const float* __restrict__ f2b,
        const float* __restrict__ g2W, const float* __restrict__ g2b,
        const float* __restrict__ o1W, const float* __restrict__ o1b,
        const float* __restrict__ o2W, const float* __restrict__ o2b,
        float* __restrict__ out) {
    __shared__ float At[NH][256];
    __shared__ float Ft[NH][256];
    __shared__ float red_m[NH];
    __shared__ float red_s[NH];
    __shared__ float cat[512];
    __shared__ float catB[320];
    __shared__ float g1s[256];
    __shared__ float x2l[NH][64];
    __shared__ float part4[4][256];
    __shared__ float part16[16][64];
    __shared__ float grow[256];
    const int b = blockIdx.x;
    const int t = threadIdx.x;
    const int wave = t >> 6;
    const int lane = t & 63;
    const int c = t & 255;
    const int quad = t >> 8;

    if (wave < NH) {
        int hv = host_idx[b * NH + wave];
        float acc = xw2[(size_t)hv * 64 + lane];
        int e0 = offs[hv], e1 = offs[hv + 1];
        for (int e = e0; e < e1; e += 8) {
            int u[8];
            #pragma unroll
            for (int i = 0; i < 8; ++i) u[i] = csr[(e + i < e1) ? (e + i) : (e1 - 1)];
            float m[8];
            #pragma unroll
            for (int i = 0; i < 8; ++i) m[i] = xw2[(size_t)u[i] * 64 + lane];
            #pragma unroll
            for (int i = 0; i < 8; ++i)
                if (e + i < e1) acc = fmaxf(acc, m[i]);
        }
        x2l[wave][lane] = fmaxf(fmaf(acc, dinv[hv], b2[lane]), 0.f);
    }
    for (int idx = t; idx < NH * 128; idx += 1024) {
        int j = idx >> 7, q = idx & 127;
        float4 v = ((const float4*)(AF + (size_t)(b * NH + j) * 512))[q];
        if (q < 64) *(float4*)&At[j][q * 4] = v;
        else        *(float4*)&Ft[j][(q - 64) * 4] = v;
    }
    __syncthreads();
    if (wave < NH) {
        float m = -3.402823466e38f;
        #pragma unroll
        for (int q = 0; q < 4; ++q) m = fmaxf(m, At[wave][q * 64 + lane]);
        #pragma unroll
        for (int off = 32; off; off >>= 1) m = fmaxf(m, __shfl_xor(m, off));
        if (lane == 0) red_m[wave] = m;
    }
    __syncthreads();
    for (int idx = t; idx < NH * 256; idx += 1024) {
        int j = idx >> 8, cc = idx & 255;
        At[j][cc] = expf(At[j][cc] - red_m[j]);
    }
    __syncthreads();
    if (wave < NH) {
        float s = 0.f;
        #pragma unroll
        for (int q = 0; q < 4; ++q) s += At[wave][q * 64 + lane];
        #pragma unroll
        for (int off = 32; off; off >>= 1) s += __shfl_xor(s, off);
        if (lane == 0) red_s[wave] = s;
    }
    __syncthreads();
    if (quad == 0) {
        float outc = 0.f;
        #pragma unroll
        for (int j = 0; j < NH; ++j) outc += At[j][c] / red_s[j] * Ft[j][c];
        cat[c] = outc;
        cat[256 + c] = g_in[b * 256 + c];
    }
    __syncthreads();
    // g1W update: 512 floats = 128 float4, 32 per quad (full coverage)
    {
        float acc = 0.f;
        const float* gwp = g1W + c;
        #pragma unroll 4
        for (int i4 = quad * 32; i4 < quad * 32 + 32; ++i4) {
            float4 cq = ((const float4*)cat)[i4];
            const float* gw4 = gwp + (size_t)i4 * 1024;
            acc = fmaf(cq.x, gw4[0], acc);
            acc = fmaf(cq.y, gw4[256], acc);
            acc = fmaf(cq.z, gw4[512], acc);
            acc = fmaf(cq.w, gw4[768], acc);
        }
        part4[quad][c] = acc;
    }
    __syncthreads();
    if (quad == 0)
        g1s[c] = cat[256 + c] + g1b[c] +
                 part4[0][c] + part4[1][c] + part4[2][c] + part4[3][c];
    __syncthreads();
    if (wave < NH) {
        float aA = a2b[lane], aF = f2b[lane];
        #pragma unroll 8
        for (int k = 0; k < 64; ++k) {
            float xv = x2l[wave][k];
            aA = fmaf(xv, a2W[k * 64 + lane], aA);
            aF = fmaf(xv, f2W[k * 64 + lane], aF);
        }
        float m = aA;
        #pragma unroll
        for (int off = 32; off; off >>= 1) m = fmaxf(m, __shfl_xor(m, off));
        float pexp = expf(aA - m);
        float s = pexp;
        #pragma unroll
        for (int off = 32; off; off >>= 1) s += __shfl_xor(s, off);
        At[wave][lane] = pexp / s * aF;
    }
    __syncthreads();
    if (t < 64) {
        float o = 0.f;
        #pragma unroll
        for (int j = 0; j < NH; ++j) o += At[j][t];
        catB[t] = o;
    }
    if (quad == 0) catB[64 + c] = g1s[c];
    __syncthreads();
    // g2W update: 320 floats = 80 float4, 20 per quad
    {
        float acc = 0.f;
        const float* gwp = g2W + c;
        #pragma unroll 4
        for (int i4 = quad * 20; i4 < quad * 20 + 20; ++i4) {
            float4 cq = ((const float4*)catB)[i4];
            const float* gw4 = gwp + (size_t)i4 * 1024;
            acc = fmaf(cq.x, gw4[0], acc);
            acc = fmaf(cq.y, gw4[256], acc);
            acc = fmaf(cq.z, gw4[512], acc);
            acc = fmaf(cq.w, gw4[768], acc);
        }
        part4[quad][c] = acc;
    }
    __syncthreads();
    if (quad == 0)
        grow[c] = g1s[c] + g2b[c] +
                  part4[0][c] + part4[1][c] + part4[2][c] + part4[3][c];
    __syncthreads();
    {
        float hp = 0.f;
        #pragma unroll
        for (int k = wave * 16; k < wave * 16 + 16; ++k)
            hp = fmaf(grow[k], o1W[(size_t)k * 64 + lane], hp);
        part16[wave][lane] = hp;
    }
    __syncthreads();
    if (wave == 0) {
        float h = o1b[lane];
        #pragma unroll
        for (int w = 0; w < 16; ++w) h += part16[w][lane];
        h = fmaxf(h, 0.f);
        float sres = h * o2W[lane];
        #pragma unroll
        for (int off = 32; off; off >>= 1) sres += __shfl_xor(sres, off);
        if (lane == 0) out[b] = sres + o2b[0];
    }
}

extern "C" void kernel_launch(void* const* d_in, const int* in_sizes, int n_in,
                              void* d_out, int out_size, void* d_ws, size_t ws_size,
                              hipStream_t stream) {
    (void)in_sizes; (void)n_in; (void)out_size;
    const float* x    = (const float*)d_in[0];
    const int* ei32   = (const int*)d_in[1];
    const long long* ei64 = (const long long*)d_in[1];
    const int* hidx   = (const int*)d_in[2];
    const float* W1 = (const float*)d_in[3],  *b1 = (const float*)d_in[4];
    const float* W2 = (const float*)d_in[5],  *b2 = (const float*)d_in[6];
    const float* a0W = (const float*)d_in[7],  *a0b = (const float*)d_in[8];
    const float* f0W = (const float*)d_in[9],  *f0b = (const float*)d_in[10];
    const float* g0W = (const float*)d_in[11], *g0b = (const float*)d_in[12];
    const float* a1W = (const float*)d_in[13], *a1b = (const float*)d_in[14];
    const float* f1W = (const float*)d_in[15], *f1b = (const float*)d_in[16];
    const float* g1W = (const float*)d_in[17], *g1b = (const float*)d_in[18];
    const float* a2W = (const float*)d_in[19], *a2b = (const float*)d_in[20];
    const float* f2W = (const float*)d_in[21], *f2b = (const float*)d_in[22];
    const float* g2W = (const float*)d_in[23], *g2b = (const float*)d_in[24];
    const float* o1W = (const float*)d_in[25], *o1b = (const float*)d_in[26];
    const float* o2W = (const float*)d_in[27], *o2b = (const float*)d_in[28];
    float* outp = (float*)d_out;

    char* p = (char*)d_ws;
    auto alloc = [&](size_t bytes) {
        char* r = p;
        p += (bytes + 255) & ~(size_t)255;
        return r;
    };
    float* dinv = (float*)alloc((size_t)N_NODES * 4);
    int* degc   = (int*)alloc((size_t)N_NODES * 4);
    int* offs   = (int*)alloc((size_t)(N_NODES + 1) * 4);
    int* csr    = (int*)alloc((size_t)N_EDGES * 4);
    int* bsums  = (int*)alloc(256 * 4);
    float* g    = (float*)alloc((size_t)B_GRAPH * 256 * 4);
    float* AF   = (float*)alloc((size_t)B_GRAPH * NH * 512 * 4);
    unsigned short* xw1b = (unsigned short*)alloc((size_t)N_NODES * 256 * 2);  // bf16
    unsigned short* x1b  = (unsigned short*)alloc((size_t)N_NODES * 256 * 2);  // bf16
    float* xw2  = (float*)alloc((size_t)N_NODES * 64 * 4);

    size_t need = (size_t)(p - (char*)d_ws);
    if (need > ws_size) {
        fprintf(stderr, "kernel_launch: ws too small (%zu needed, %zu have)\n", need, ws_size);
        return;
    }

    (void)hipMemsetAsync(degc, 0, (size_t)N_NODES * 4, stream);
    count_deg<<<1600, 256, 0, stream>>>(ei32, ei64, degc);
    scan_block_sums<<<200, 256, 0, stream>>>(degc, bsums);
    scan_finalize<<<200, 256, 0, stream>>>(degc, offs, dinv, bsums);

    // gemm1 (64x64 4x4, bf16 out) | af0 | fill_csr
    fused_gemm1<<<5216, 256, 0, stream>>>(
        x, W1, (float*)xw1b, dinv, ei32, ei64, degc, csr,
        hidx, a0W, a0b, f0W, f0b, AF);
    // attn reduce 0 | agg (bf16 gather, bf16 out)
    fused_agg256<<<256 + 12800, 256, 0, stream>>>((const uint2*)xw1b, dinv, offs, csr,
                                                  b1, (uint2*)x1b, AF, g0W, g0b,
                                                  nullptr, g);
    // gemm2 (128x64 8x4, bf16 in, fp32 out) | af1 (bf16 in)
    fused_gemm2<<<816, 256, 0, stream>>>(
        (const float*)x1b, W2, xw2, dinv, hidx, a1W, a1b, f1W, f1b, AF);
    // per-graph (1024 thr): reduce1 + host-only agg + attn2 + g2 update + head
    attn_graph_head<<<256, 1024, 0, stream>>>(
        AF, g1W, g1b, g, xw2, dinv, offs, csr, b2, hidx,
        a2W, a2b, f2W, f2b, g2W, g2b, o1W, o1b, o2W, o2b, outp);
}